// Round 1
// baseline (845.852 us; speedup 1.0000x reference)
//
#include <hip/hip_runtime.h>
#include <math.h>

#define NFEAT 256
#define NHID 128
#define NCLASS 40

// ---------------- degree / CSR build ----------------

__global__ void k_init(int* cnt, int* cursor, int n) {
    int i = blockIdx.x * blockDim.x + threadIdx.x;
    if (i < n) { cnt[i] = 0; cursor[i] = 0; }
}

__global__ void k_count(const int* __restrict__ dst, int* __restrict__ cnt, int E) {
    int e = blockIdx.x * blockDim.x + threadIdx.x;
    if (e < E) atomicAdd(&cnt[dst[e]], 1);
}

__global__ void k_dinv(const int* __restrict__ cnt, float* __restrict__ dinv, int n) {
    int i = blockIdx.x * blockDim.x + threadIdx.x;
    if (i < n) dinv[i] = rsqrtf((float)cnt[i] + 1.0f);
}

// exclusive scan, 2048 elements/block (256 thr x 8)
__global__ void k_scan_local(const int* __restrict__ in, int* __restrict__ out,
                             int* __restrict__ bsum, int n) {
    __shared__ int ts[256];
    int tid = threadIdx.x;
    int base = blockIdx.x * 2048 + tid * 8;
    int v[8]; int s = 0;
#pragma unroll
    for (int i = 0; i < 8; i++) { int idx = base + i; v[i] = (idx < n) ? in[idx] : 0; s += v[i]; }
    ts[tid] = s;
    __syncthreads();
    for (int off = 1; off < 256; off <<= 1) {
        int t = (tid >= off) ? ts[tid - off] : 0;
        __syncthreads();
        ts[tid] += t;
        __syncthreads();
    }
    int run = ts[tid] - s;
#pragma unroll
    for (int i = 0; i < 8; i++) { int idx = base + i; if (idx < n) out[idx] = run; run += v[i]; }
    if (tid == 255) bsum[blockIdx.x] = ts[255];
}

__global__ void k_scan_bsum(int* bsum, int nb) {
    int tid = threadIdx.x;           // single wave of 64, nb <= 64
    int v = (tid < nb) ? bsum[tid] : 0;
    int orig = v;
    for (int off = 1; off < 64; off <<= 1) {
        int t = __shfl_up(v, off, 64);
        if (tid >= off) v += t;
    }
    if (tid < nb) bsum[tid] = v - orig;   // exclusive block offsets
}

__global__ void k_scan_add(int* __restrict__ out, const int* __restrict__ bsum, int n, int E) {
    int b = blockIdx.x;
    int base = b * 2048 + threadIdx.x * 8;
    int add = bsum[b];
#pragma unroll
    for (int i = 0; i < 8; i++) { int idx = base + i; if (idx < n) out[idx] += add; }
    if (b == 0 && threadIdx.x == 0) out[n] = E;
}

__global__ void k_fill(const int* __restrict__ src, const int* __restrict__ dst,
                       const int* __restrict__ row_ptr, int* __restrict__ cursor,
                       int* __restrict__ col, int E) {
    int e = blockIdx.x * blockDim.x + threadIdx.x;
    if (e < E) {
        int d = dst[e];
        int p = row_ptr[d] + atomicAdd(&cursor[d], 1);
        col[p] = src[e];
    }
}

// ---------------- GEMM: C[n,128] = A[n,K] @ W[K,128] ----------------
// block tile 64x128, 256 threads, micro-tile 4x8 (cols tx*4 and tx*4+64)

template<int K>
__global__ __launch_bounds__(256) void k_gemm_bn128(const float* __restrict__ A,
                                                    const float* __restrict__ W,
                                                    float* __restrict__ C, int n) {
    const int BM = 64, BN = 128, BK = 64;
    __shared__ float As[BK][BM + 4];   // transposed A tile
    __shared__ float Ws[BK][BN + 4];
    const int tid = threadIdx.x;
    const int tx = tid & 15, ty = tid >> 4;
    const int row0 = blockIdx.x * BM;
    float acc[4][8];
#pragma unroll
    for (int i = 0; i < 4; i++)
#pragma unroll
        for (int j = 0; j < 8; j++) acc[i][j] = 0.f;

    for (int k0 = 0; k0 < K; k0 += BK) {
#pragma unroll
        for (int p = 0; p < 4; p++) {
            int r = p * 16 + ty;        // 0..63 tile row
            int c = tx * 4;             // 0..60 tile col (k)
            float4 v = make_float4(0.f, 0.f, 0.f, 0.f);
            if (row0 + r < n) v = *(const float4*)&A[(size_t)(row0 + r) * K + k0 + c];
            As[c + 0][r] = v.x; As[c + 1][r] = v.y; As[c + 2][r] = v.z; As[c + 3][r] = v.w;
        }
#pragma unroll
        for (int p = 0; p < 8; p++) {
            int r = p * 8 + (tid >> 5);
            int c = (tid & 31) * 4;
            *(float4*)&Ws[r][c] = *(const float4*)&W[(size_t)(k0 + r) * BN + c];
        }
        __syncthreads();
#pragma unroll
        for (int kk = 0; kk < BK; kk++) {
            float4 a  = *(const float4*)&As[kk][ty * 4];
            float4 bq0 = *(const float4*)&Ws[kk][tx * 4];
            float4 bq1 = *(const float4*)&Ws[kk][tx * 4 + 64];
            float av[4] = {a.x, a.y, a.z, a.w};
            float bv[8] = {bq0.x, bq0.y, bq0.z, bq0.w, bq1.x, bq1.y, bq1.z, bq1.w};
#pragma unroll
            for (int i = 0; i < 4; i++)
#pragma unroll
                for (int j = 0; j < 8; j++) acc[i][j] = fmaf(av[i], bv[j], acc[i][j]);
        }
        __syncthreads();
    }
#pragma unroll
    for (int i = 0; i < 4; i++) {
        int row = row0 + ty * 4 + i;
        if (row < n) {
            *(float4*)&C[(size_t)row * BN + tx * 4]      = make_float4(acc[i][0], acc[i][1], acc[i][2], acc[i][3]);
            *(float4*)&C[(size_t)row * BN + 64 + tx * 4] = make_float4(acc[i][4], acc[i][5], acc[i][6], acc[i][7]);
        }
    }
}

// ---------------- GEMM: C[n,40] = A[n,128] @ W[128,40] ----------------

__global__ __launch_bounds__(256) void k_gemm40(const float* __restrict__ A,
                                                const float* __restrict__ W,
                                                float* __restrict__ C, int n) {
    const int BM = 64, K = 128, BN = 40;
    __shared__ float As[BM][K + 4];
    __shared__ float Ws[K * BN];
    int tid = threadIdx.x;
    int row0 = blockIdx.x * BM;
#pragma unroll
    for (int p = 0; p < 5; p++) {                  // 1280 float4 of W
        int i = p * 256 + tid;
        *(float4*)&Ws[i * 4] = *(const float4*)&W[i * 4];
    }
#pragma unroll
    for (int p = 0; p < 8; p++) {
        int r = p * 8 + (tid >> 5);
        int c = (tid & 31) * 4;
        float4 v = make_float4(0.f, 0.f, 0.f, 0.f);
        if (row0 + r < n) v = *(const float4*)&A[(size_t)(row0 + r) * K + c];
        *(float4*)&As[r][c] = v;
    }
    __syncthreads();
    int tx = tid & 7, ty = tid >> 3;
    int r0 = ty * 2, c0 = tx * 5;
    float acc[2][5];
#pragma unroll
    for (int i = 0; i < 2; i++)
#pragma unroll
        for (int j = 0; j < 5; j++) acc[i][j] = 0.f;
#pragma unroll 8
    for (int k = 0; k < K; k++) {
        float a0 = As[r0][k], a1 = As[r0 + 1][k];
#pragma unroll
        for (int j = 0; j < 5; j++) {
            float w = Ws[k * BN + c0 + j];
            acc[0][j] = fmaf(a0, w, acc[0][j]);
            acc[1][j] = fmaf(a1, w, acc[1][j]);
        }
    }
#pragma unroll
    for (int i = 0; i < 2; i++) {
        int row = row0 + r0 + i;
        if (row < n) {
#pragma unroll
            for (int j = 0; j < 5; j++) C[(size_t)row * BN + c0 + j] = acc[i][j];
        }
    }
}

// ---------------- aggregation (gather over CSR-by-dst) ----------------

template<bool RELU>
__global__ __launch_bounds__(128) void k_agg128(const float* __restrict__ h,
                                                const float* __restrict__ dinv,
                                                const int* __restrict__ row_ptr,
                                                const int* __restrict__ col,
                                                const float* __restrict__ bias,
                                                float* __restrict__ out) {
    int n = blockIdx.x;
    int f = threadIdx.x;
    float dn = dinv[n];
    float acc = dn * h[(size_t)n * NHID + f];           // self-loop: (dn*h)*dn later
    int e1 = row_ptr[n + 1];
    for (int e = row_ptr[n]; e < e1; ++e) {
        int s = col[e];
        acc = fmaf(dinv[s], h[(size_t)s * NHID + f], acc);
    }
    float r = fmaf(dn, acc, bias[f]);
    out[(size_t)n * NHID + f] = RELU ? fmaxf(r, 0.f) : r;
}

__global__ __launch_bounds__(64) void k_agg40_lsm(const float* __restrict__ h,
                                                  const float* __restrict__ dinv,
                                                  const int* __restrict__ row_ptr,
                                                  const int* __restrict__ col,
                                                  const float* __restrict__ bias,
                                                  float* __restrict__ out) {
    int n = blockIdx.x;
    int f = threadIdx.x;
    bool act = f < NCLASS;
    float dn = dinv[n];
    float acc = act ? dn * h[(size_t)n * NCLASS + f] : 0.f;
    int e1 = row_ptr[n + 1];
    for (int e = row_ptr[n]; e < e1; ++e) {
        int s = col[e];
        if (act) acc = fmaf(dinv[s], h[(size_t)s * NCLASS + f], acc);
    }
    float z = act ? fmaf(dn, acc, bias[f]) : -INFINITY;
    float m = z;
#pragma unroll
    for (int off = 32; off; off >>= 1) m = fmaxf(m, __shfl_xor(m, off, 64));
    float p = act ? expf(z - m) : 0.f;
    float ssum = p;
#pragma unroll
    for (int off = 32; off; off >>= 1) ssum += __shfl_xor(ssum, off, 64);
    if (act) out[(size_t)n * NCLASS + f] = z - m - logf(ssum);
}

// ---------------- launch ----------------

extern "C" void kernel_launch(void* const* d_in, const int* in_sizes, int n_in,
                              void* d_out, int out_size, void* d_ws, size_t ws_size,
                              hipStream_t stream) {
    const float* x  = (const float*)d_in[0];
    const int*   ei = (const int*)d_in[1];
    const float* W1 = (const float*)d_in[2];
    const float* b1 = (const float*)d_in[3];
    const float* W2 = (const float*)d_in[4];
    const float* b2 = (const float*)d_in[5];
    const float* W3 = (const float*)d_in[6];
    const float* b3 = (const float*)d_in[7];
    float* out = (float*)d_out;
    const int N = in_sizes[0] / NFEAT;
    const int E = in_sizes[1] / 2;
    const int* src = ei;
    const int* dst = ei + E;

    char* ws = (char*)d_ws;
    size_t off = 0;
    auto alloc = [&](size_t bytes) -> void* {
        void* p = ws + off;
        off += (bytes + 255) & ~(size_t)255;
        return p;
    };
    int*   cnt     = (int*)alloc((size_t)N * 4);
    float* dinv    = (float*)alloc((size_t)N * 4);
    int*   cursor  = (int*)alloc((size_t)N * 4);
    int*   row_ptr = (int*)alloc((size_t)(N + 1) * 4);
    int*   bsum    = (int*)alloc(64 * 4);
    int*   col     = (int*)alloc((size_t)E * 4);
    float* bufA    = (float*)alloc((size_t)N * NHID * 4);
    float* bufB    = (float*)alloc((size_t)N * NHID * 4);
    (void)ws_size; (void)n_in; (void)out_size;

    int NB = (N + 2047) / 2048;

    k_init<<<(N + 255) / 256, 256, 0, stream>>>(cnt, cursor, N);
    k_count<<<(E + 255) / 256, 256, 0, stream>>>(dst, cnt, E);
    k_dinv<<<(N + 255) / 256, 256, 0, stream>>>(cnt, dinv, N);
    k_scan_local<<<NB, 256, 0, stream>>>(cnt, row_ptr, bsum, N);
    k_scan_bsum<<<1, 64, 0, stream>>>(bsum, NB);
    k_scan_add<<<NB, 256, 0, stream>>>(row_ptr, bsum, N, E);
    k_fill<<<(E + 255) / 256, 256, 0, stream>>>(src, dst, row_ptr, cursor, col, E);

    // layer 1: h1 = x @ W1 -> bufA ; a1 = relu(agg(h1)+b1) -> bufB
    k_gemm_bn128<NFEAT><<<(N + 63) / 64, 256, 0, stream>>>(x, W1, bufA, N);
    k_agg128<true><<<N, 128, 0, stream>>>(bufA, dinv, row_ptr, col, b1, bufB);
    // layer 2
    k_gemm_bn128<NHID><<<(N + 63) / 64, 256, 0, stream>>>(bufB, W2, bufA, N);
    k_agg128<true><<<N, 128, 0, stream>>>(bufA, dinv, row_ptr, col, b2, bufB);
    // layer 3 + log_softmax
    k_gemm40<<<(N + 63) / 64, 256, 0, stream>>>(bufB, W3, bufA, N);
    k_agg40_lsm<<<N, 64, 0, stream>>>(bufA, dinv, row_ptr, col, b3, out);
}